// Round 13
// baseline (709.029 us; speedup 1.0000x reference)
//
#include <hip/hip_runtime.h>
#include <hip/hip_cooperative_groups.h>
#include <cstdint>

namespace cg = cooperative_groups;

#define N 8192
#define NT 128     // 64-col chunks per row == 64-row tiles
#define NROUNDS 6
typedef unsigned long long u64;
typedef unsigned int u32;

// d_ws layout (256-aligned, total ~8.7 MB << ws_size)
#define OFF_BX1 (size_t)0
#define OFF_BY1 (size_t)32768
#define OFF_BX2 (size_t)65536
#define OFF_BY2 (size_t)98304
#define OFF_SS  (size_t)131072
#define OFF_AR  (size_t)163840
#define OFF_CL  (size_t)196608
#define OFF_CNT (size_t)229376
#define OFF_PRB (size_t)262144
#define OFF_Y2F (size_t)294912
#define OFF_D   (size_t)360448
#define OFF_S   (size_t)361472
#define OFF_MT  (size_t)362752

__device__ inline u64 readlane64(u64 v, int lane) {
  u32 lo = (u32)__builtin_amdgcn_readlane((int)(u32)v, lane);
  u32 hi = (u32)__builtin_amdgcn_readlane((int)(u32)(v >> 32), lane);
  return ((u64)hi << 32) | lo;
}

struct SmA { u64 tile[1024]; int red[8][32]; };   // rank
struct SmC { u64 Dl[NT]; u64 Sl[NT]; u64 bw[3][4]; };  // rounds
struct SmD { int ulist[N]; };                     // fix (32 KB = union max)
struct SmE { u64 hlds[NT]; int red2[4][64]; };    // cluster
union SmU { SmA a; SmC c; SmD d; SmE e; };

// ---------------------------------------------------------------------------
// ONE cooperative kernel. 256 blocks x 256 thr (1 block/CU, co-resident by
// cooperative-launch guarantee). Phases separated by __threadfence()+
// grid.sync() (device-scope fences handle cross-XCD L2 non-coherence; all
// cross-block publishes are device-scope atomics or fenced plain stores).
// R12 lesson: per-kernel work is all <41us; the cost left is ~12 dispatch
// gaps + fills -> collapse to 1 dispatch, pay ~10 grid syncs instead.
// ---------------------------------------------------------------------------
__global__ __launch_bounds__(256, 1) void k_mega(const float* __restrict__ boxes,
                                                 const float* __restrict__ scores,
                                                 const int* __restrict__ num_models,
                                                 float* __restrict__ out,
                                                 char* __restrict__ ws) {
#pragma clang fp contract(off)
  __shared__ SmU sm;
  cg::grid_group grid = cg::this_grid();

  float* bx1s  = (float*)(ws + OFF_BX1);
  float* by1s  = (float*)(ws + OFF_BY1);
  float* bx2s  = (float*)(ws + OFF_BX2);
  float* by2s  = (float*)(ws + OFF_BY2);
  float* ss    = (float*)(ws + OFF_SS);
  float* areas = (float*)(ws + OFF_AR);
  int* cluster = (int*)(ws + OFF_CL);
  int* cnt     = (int*)(ws + OFF_CNT);
  float* prob  = (float*)(ws + OFF_PRB);
  u64* y2f     = (u64*)(ws + OFF_Y2F);
  u64* D       = (u64*)(ws + OFF_D);
  u64* S       = (u64*)(ws + OFF_S);
  u64* mtile   = (u64*)(ws + OFF_MT);

  const int t = threadIdx.x;
  const int b = blockIdx.x;
  const int w = t >> 6, l = t & 63;

  // ===== Phase A: rank + scatter + init (R12 k_rank0, validated) =====
  {
    int s = t >> 5, ei = t & 31;
    int e = b * 32 + ei;
    u64 ke = ((u64)__float_as_uint(scores[e]) << 32) | (u32)(0xFFFFFFFFu - (u32)e);
    int c = 0;
    for (int j0 = 0; j0 < N; j0 += 1024) {
      __syncthreads();
      for (int q = t; q < 1024; q += 256) {
        int j = j0 + q;
        sm.a.tile[q] = ((u64)__float_as_uint(scores[j]) << 32) | (u32)(0xFFFFFFFFu - (u32)j);
      }
      __syncthreads();
      int k0 = s * 128;
#pragma unroll 8
      for (int k = 0; k < 128; ++k) c += (sm.a.tile[k0 + k] > ke) ? 1 : 0;
    }
    sm.a.red[s][ei] = c;
    __syncthreads();
    if (t < 32) {
      int r = 0;
#pragma unroll
      for (int q = 0; q < 8; ++q) r += sm.a.red[q][t];
      int i = b * 32 + t;
      float x1 = fminf(fmaxf(boxes[i * 4 + 0], 0.0f), 1920.0f);
      float y1 = fminf(fmaxf(boxes[i * 4 + 1], 0.0f), 1080.0f);
      float x2 = fminf(fmaxf(boxes[i * 4 + 2], 0.0f), 1920.0f);
      float y2 = fminf(fmaxf(boxes[i * 4 + 3], 0.0f), 1080.0f);
      bx1s[r] = x1; by1s[r] = y1; bx2s[r] = x2; by2s[r] = y2;
      ss[r] = scores[i];
      areas[r] = (x2 - x1 + 1.0f) * (y2 - y1 + 1.0f);
      cnt[i] = 0; prob[i] = 0.0f; y2f[i] = 0ull;
    }
    if (b == 0) {
      if (t < NT) D[t] = 0ull;
      else if (t < 2 * NT) S[t - NT] = 0ull;
    }
  }
  __threadfence();
  grid.sync();

  // ===== Phase B: adjacency, wave-per-tile, shfl broadcast (no LDS/barriers)
  // Band trick (R8, validated): only |2*inter-uni| <= 1e-6*uni lanes divide.
  {
    const int NP = NT * (NT + 1) / 2;   // 8256 lower-triangle tiles
    for (int p = b * 4 + w; p < NP; p += 1024) {
      int gy = (int)((sqrtf(8.0f * (float)p + 1.0f) - 1.0f) * 0.5f);
      while ((gy + 1) * (gy + 2) / 2 <= p) ++gy;
      while (gy * (gy + 1) / 2 > p) --gy;
      int gx = p - gy * (gy + 1) / 2;
      int j = gx * 64 + l, i = gy * 64 + l;
      float jx1v = bx1s[j], jy1v = by1s[j], jx2v = bx2s[j], jy2v = by2s[j], jav = areas[j];
      float x1 = bx1s[i], y1 = by1s[i], x2 = bx2s[i], y2 = by2s[i], ai = areas[i];
      u64 bits = 0;
#pragma unroll 4
      for (int jj = 0; jj < 64; ++jj) {
        float ix1 = fmaxf(x1, __shfl(jx1v, jj));
        float iy1 = fmaxf(y1, __shfl(jy1v, jj));
        float ix2 = fminf(x2, __shfl(jx2v, jj));
        float iy2 = fminf(y2, __shfl(jy2v, jj));
        float iw = fmaxf(ix2 - ix1 + 1.0f, 0.0f);
        float ih = fmaxf(iy2 - iy1 + 1.0f, 0.0f);
        float inter = iw * ih;
        float uni = (ai + __shfl(jav, jj)) - inter;
        float tt = inter + inter;
        bool gt = tt > uni;
        bool amb = fabsf(tt - uni) <= 1e-6f * uni;
        if (__ballot(amb) != 0ull) {      // ~never taken
          float iou = inter / uni;        // exact IEEE div, matches numpy
          if (amb) gt = iou > 0.5f;
        }
        bits |= ((u64)gt) << jj;
      }
      mtile[((size_t)gy * NT + gx) * 64 + l] = bits;
      if (gx != gy) {
        u64 tb = 0;
#pragma unroll 8
        for (int cc = 0; cc < 64; ++cc) {
          u64 wb = __ballot((bits >> cc) & 1ull);
          tb = (l == cc) ? wb : tb;
        }
        mtile[((size_t)gx * NT + gy) * 64 + l] = tb;
      }
    }
  }
  __threadfence();
  grid.sync();

  // ===== Phase C: NROUNDS monotone rounds + exact rE==0 resolve (R11/12) ====
  // grid.sync gives each round a coherent D/S snapshot (what R10's chaotic
  // in-kernel version lacked). Blocks 0..127 own tiles; others just sync.
  for (int it = 0; it < NROUNDS; ++it) {
    __syncthreads();
    if (t < NT) sm.c.Dl[t] = D[t];
    else sm.c.Sl[t - NT] = S[t - NT];
    __syncthreads();
    if (b < NT) {
      int gy = b;
      u64 classified = sm.c.Dl[gy] | sm.c.Sl[gy];
      if (classified != ~0ull) {         // block-uniform
        bool unk = !((classified >> l) & 1ull);
        u64 anyD = 0, anyU = 0, anyE = 0;
        if (unk) {
          int k0 = 32 * w, k1 = min(k0 + 32, gy + 1);
          for (int k = k0; k < k1; ++k) {
            u64 m = mtile[((size_t)gy * NT + k) * 64 + l];
            if (k == gy) {
              m &= (1ull << l) - 1ull;    // strictly earlier within own tile
              anyD |= m & sm.c.Dl[k];
              anyU |= m & ~sm.c.Sl[k];
            } else {
              anyD |= m & sm.c.Dl[k];
              anyU |= m & ~sm.c.Sl[k];
              anyE |= m & ~(sm.c.Sl[k] | sm.c.Dl[k]);
            }
          }
        }
        u64 bD = __ballot(anyD != 0ull), bU = __ballot(anyU != 0ull), bE = __ballot(anyE != 0ull);
        if (l == 0) { sm.c.bw[0][w] = bD; sm.c.bw[1][w] = bU; sm.c.bw[2][w] = bE; }
        __syncthreads();
        u64 rD = sm.c.bw[0][0] | sm.c.bw[0][1] | sm.c.bw[0][2] | sm.c.bw[0][3];
        u64 rU = sm.c.bw[1][0] | sm.c.bw[1][1] | sm.c.bw[1][2] | sm.c.bw[1][3];
        u64 rE = sm.c.bw[2][0] | sm.c.bw[2][1] | sm.c.bw[2][2] | sm.c.bw[2][3];
        u64 unkb = ~classified;
        if (rE == 0ull) {
          // exact resolve: unknown rows' earlier prefixes are final
          if (w == 0) {
            u64 dAA = mtile[((size_t)gy * NT + gy) * 64 + l];
            u64 heads = 0, todo = unkb & ~rD;
            while (todo) {
              int i2 = __builtin_ctzll(todo);
              heads |= 1ull << i2;
              todo &= ~readlane64(dAA, i2);
            }
            if (l == 0) {
              if (heads) atomicOr(&D[gy], heads);
              u64 ns = unkb & ~heads;
              if (ns) atomicOr(&S[gy], ns);
            }
          }
        } else if (t == 0) {
          u64 newS = unkb & rD;
          u64 newD2 = unkb & ~rD & ~rU;
          if (newS) atomicOr(&S[gy], newS);
          if (newD2) atomicOr(&D[gy], newD2);
        }
      }
    }
    __threadfence();
    grid.sync();
  }

  // ===== Phase D: exact serial cleanup (block 0, wave 0; no __syncthreads) ==
  __syncthreads();
  if (b == 0 && w == 0) {
    u64 D0 = D[l], D1 = D[64 + l];
    u64 S0 = S[l], S1 = S[64 + l];
    u64 u0 = ~(D0 | S0), u1 = ~(D1 | S1);
    int c0 = __popcll(u0), c1 = __popcll(u1);
    int p0 = c0, p1 = c1;
    for (int d2 = 1; d2 < 64; d2 <<= 1) {
      int v0 = __shfl_up(p0, d2), v1 = __shfl_up(p1, d2);
      if (l >= d2) { p0 += v0; p1 += v1; }
    }
    int t0s = __shfl(p0, 63);
    int M = t0s + __shfl(p1, 63);
    {
      int o = p0 - c0; u64 v = u0;
      while (v) { int bb = __builtin_ctzll(v); v &= v - 1; sm.d.ulist[o++] = l * 64 + bb; }
      o = t0s + p1 - c1; v = u1;
      while (v) { int bb = __builtin_ctzll(v); v &= v - 1; sm.d.ulist[o++] = (64 + l) * 64 + bb; }
    }
    asm volatile("s_waitcnt lgkmcnt(0)" ::: "memory");  // ulist visible in-wave
    if (M > 0) {
      u64 rx[8], ry[8];
      int pj[8];
      auto fetch = [&](int q, int j) {
        pj[q] = j;
        int jt = j >> 6, jl = j & 63;
        rx[q] = mtile[((size_t)jt * NT + l) * 64 + jl];
        ry[q] = mtile[((size_t)jt * NT + 64 + l) * 64 + jl];
      };
#pragma unroll
      for (int q = 0; q < 8; ++q) fetch(q, sm.d.ulist[q < M ? q : M - 1]);
      for (int m = 0; m < M; ++m) {
        int slot = m & 7;
        int j = pj[slot];
        u64 vx = rx[slot], vy = ry[slot];
        int jt = j >> 6;
        u64 bm = (1ull << (j & 63)) - 1ull;
        u64 m0 = (l < jt) ? ~0ull : ((l == jt) ? bm : 0ull);
        u64 m1 = (64 + l < jt) ? ~0ull : ((64 + l == jt) ? bm : 0ull);
        bool hit = ((vx & D0 & m0) | (vy & D1 & m1)) != 0ull;
        bool head = (__ballot(hit) == 0ull);
        u64 bset = 1ull << (j & 63);
        D0 |= (head && (l == jt)) ? bset : 0ull;
        D1 |= (head && (64 + l == jt)) ? bset : 0ull;
        int nm2 = m + 8;
        fetch(slot, sm.d.ulist[nm2 < M ? nm2 : M - 1]);
      }
    }
    D[l] = D0;
    D[64 + l] = D1;
  }
  __threadfence();
  grid.sync();

  // ===== Phase E: cluster assignment + segment atomics (R12, validated) =====
  if (b < NT) {
    __syncthreads();
    if (t < NT) sm.e.hlds[t] = D[t];
    __syncthreads();
    int gy = b;
    int best = 0x7fffffff;
    for (int kk = 0; kk < 32; ++kk) {
      int k = 32 * w + kk;
      u64 v = mtile[((size_t)gy * NT + k) * 64 + l] & sm.e.hlds[k];
      if (v && best == 0x7fffffff) best = k * 64 + __builtin_ctzll(v);
    }
    sm.e.red2[w][l] = best;
    __syncthreads();
    if (w == 0) {
      int bb = min(min(sm.e.red2[0][l], sm.e.red2[1][l]), min(sm.e.red2[2][l], sm.e.red2[3][l]));
      int j = gy * 64 + l;
      cluster[j] = bb;
      atomicAdd(&cnt[bb], 1);
      atomicAdd(&prob[bb], ss[j]);
      u64 key = ((u64)__float_as_uint(by2s[j]) << 32) | (u32)(0xFFFFFFFFu - (u32)j);
      atomicMax(&y2f[bb], key);   // by2>0: bit order == float order; ~j = min-j tiebreak
    }
  }
  __threadfence();
  grid.sync();

  // ===== Phase F: outputs =====
  if (t < 32) {
    int j = b * 32 + t;
    int c = cluster[j];
    int nm = num_models[0];
    bool valid = (float)cnt[c] >= (float)nm / 3.0f;
    int jf = (int)(0xFFFFFFFFu - (u32)(y2f[c] & 0xFFFFFFFFull));
    bool keep = (jf == j) && valid;
    float o0 = 0.f, o1 = 0.f, o2 = 0.f, o3 = 0.f, o4 = 0.f;
    if (keep) {
      o0 = bx1s[j]; o1 = by1s[j]; o2 = bx2s[j]; o3 = by2s[j];
      o4 = prob[c] / (float)nm;
    }
    out[j * 5 + 0] = o0;
    out[j * 5 + 1] = o1;
    out[j * 5 + 2] = o2;
    out[j * 5 + 3] = o3;
    out[j * 5 + 4] = o4;
    out[N * 5 + j] = keep ? 1.0f : 0.0f;
  }
}

// ---------------------------------------------------------------------------
extern "C" void kernel_launch(void* const* d_in, const int* in_sizes, int n_in,
                              void* d_out, int out_size, void* d_ws, size_t ws_size,
                              hipStream_t stream) {
  const float* boxes = (const float*)d_in[0];
  const float* scores = (const float*)d_in[1];
  const int* num_models = (const int*)d_in[2];
  float* out = (float*)d_out;
  char* ws = (char*)d_ws;

  void* args[] = {(void*)&boxes, (void*)&scores, (void*)&num_models,
                  (void*)&out, (void*)&ws};
  hipLaunchCooperativeKernel((const void*)k_mega, dim3(256), dim3(256),
                             args, 0, stream);
}

// Round 14
// 191.898 us; speedup vs baseline: 3.6948x; 3.6948x over previous
//
#include <hip/hip_runtime.h>
#include <cstdint>

#define N 8192
#define NT 128      // 64-col chunks per row (N/64)
#define NPLAIN 4    // plain k_round launches before the merged round+fix
typedef unsigned long long u64;
typedef unsigned int u32;

__device__ inline u64 readlane64(u64 v, int lane) {
  u32 lo = (u32)__builtin_amdgcn_readlane((int)(u32)v, lane);
  u32 hi = (u32)__builtin_amdgcn_readlane((int)(u32)(v >> 32), lane);
  return ((u64)hi << 32) | lo;
}

// ---------------------------------------------------------------------------
// K1: rank + scatter + init (R12, validated). Block b owns elements
// [32b,32b+32); thread (s,e) counts sub-slice s for element e; keys are a
// pure function of (score,i) -> recomputed, no atomics; t<32 scatters.
// ---------------------------------------------------------------------------
__global__ __launch_bounds__(256) void k_rank0(const float* __restrict__ scores,
                                               const float* __restrict__ boxes,
                                               float* __restrict__ bx1s, float* __restrict__ by1s,
                                               float* __restrict__ bx2s, float* __restrict__ by2s,
                                               float* __restrict__ ss, float* __restrict__ areas,
                                               int* __restrict__ cnt,
                                               float* __restrict__ prob,
                                               u64* __restrict__ y2f,
                                               u64* __restrict__ D,
                                               u64* __restrict__ S) {
#pragma clang fp contract(off)
  __shared__ u64 tile[1024];
  __shared__ int red[8][32];
  int t = threadIdx.x;
  int s = t >> 5, ei = t & 31;
  int e = blockIdx.x * 32 + ei;
  u64 ke = ((u64)__float_as_uint(scores[e]) << 32) | (u32)(0xFFFFFFFFu - (u32)e);
  int c = 0;
  for (int j0 = 0; j0 < N; j0 += 1024) {
    __syncthreads();
    for (int q = t; q < 1024; q += 256) {
      int j = j0 + q;
      tile[q] = ((u64)__float_as_uint(scores[j]) << 32) | (u32)(0xFFFFFFFFu - (u32)j);
    }
    __syncthreads();
    int k0 = s * 128;
#pragma unroll 8
    for (int k = 0; k < 128; ++k) c += (tile[k0 + k] > ke) ? 1 : 0;
  }
  red[s][ei] = c;
  __syncthreads();
  if (t < 32) {
    int r = 0;
#pragma unroll
    for (int q = 0; q < 8; ++q) r += red[q][t];
    int i = blockIdx.x * 32 + t;
    float x1 = fminf(fmaxf(boxes[i * 4 + 0], 0.0f), 1920.0f);
    float y1 = fminf(fmaxf(boxes[i * 4 + 1], 0.0f), 1080.0f);
    float x2 = fminf(fmaxf(boxes[i * 4 + 2], 0.0f), 1920.0f);
    float y2 = fminf(fmaxf(boxes[i * 4 + 3], 0.0f), 1080.0f);
    bx1s[r] = x1; by1s[r] = y1; bx2s[r] = x2; by2s[r] = y2;
    ss[r] = scores[i];
    areas[r] = (x2 - x1 + 1.0f) * (y2 - y1 + 1.0f);
    cnt[i] = 0; prob[i] = 0.0f; y2f[i] = 0ull;
  }
  if (blockIdx.x == 0) {
    if (t < NT) D[t] = 0ull;
    else if (t < 2 * NT) S[t - NT] = 0ull;
  }
}

// ---------------------------------------------------------------------------
// K2: adjacency, LOWER TRIANGLE ONLY (R14): nothing downstream reads the
// upper half — k_round uses k<=gy; k_fix masks k>jt; cluster[j]'s min head
// is always <= j (an adjacent earlier head would have suppressed j). Drops
// the 64-ballot transpose and half the stores vs R12. Band trick (R8,
// validated): only |2*inter-uni| <= 1e-6*uni lanes take the exact IEEE div.
// ---------------------------------------------------------------------------
__global__ __launch_bounds__(256) void k_adj(const float* __restrict__ bx1s, const float* __restrict__ by1s,
                                             const float* __restrict__ bx2s, const float* __restrict__ by2s,
                                             const float* __restrict__ areas,
                                             u64* __restrict__ mtile) {
#pragma clang fp contract(off)
  __shared__ float jx1[4][64], jy1[4][64], jx2[4][64], jy2[4][64], ja[4][64];
  int w = threadIdx.x >> 6, l = threadIdx.x & 63;
  int p = blockIdx.x * 4 + w;
  int gy = (int)((sqrtf(8.0f * (float)p + 1.0f) - 1.0f) * 0.5f);
  while ((gy + 1) * (gy + 2) / 2 <= p) ++gy;
  while (gy * (gy + 1) / 2 > p) --gy;
  int gx = p - gy * (gy + 1) / 2;

  int j = gx * 64 + l;
  jx1[w][l] = bx1s[j]; jy1[w][l] = by1s[j]; jx2[w][l] = bx2s[j]; jy2[w][l] = by2s[j]; ja[w][l] = areas[j];
  __syncthreads();
  int i = gy * 64 + l;
  float x1 = bx1s[i], y1 = by1s[i], x2 = bx2s[i], y2 = by2s[i], ai = areas[i];
  u64 bits = 0;
#pragma unroll 4
  for (int jj = 0; jj < 64; ++jj) {
    float ix1 = fmaxf(x1, jx1[w][jj]);
    float iy1 = fmaxf(y1, jy1[w][jj]);
    float ix2 = fminf(x2, jx2[w][jj]);
    float iy2 = fminf(y2, jy2[w][jj]);
    float iw = fmaxf(ix2 - ix1 + 1.0f, 0.0f);
    float ih = fmaxf(iy2 - iy1 + 1.0f, 0.0f);
    float inter = iw * ih;
    float uni = (ai + ja[w][jj]) - inter;   // uni > 0 always (areas >= 1)
    float t = inter + inter;                // exact (x2)
    bool gt = t > uni;
    bool amb = fabsf(t - uni) <= 1e-6f * uni;
    if (__ballot(amb) != 0ull) {            // ~never taken
      float iou = inter / uni;              // exact IEEE div, matches numpy
      if (amb) gt = iou > 0.5f;
    }
    bits |= ((u64)gt) << jj;
  }
  mtile[((size_t)gy * NT + gx) * 64 + l] = bits;
}

// ---------------------------------------------------------------------------
// shared round body (R11/R12, validated): monotone rules + exact rE==0
// resolve. Suppressed if some earlier neighbor in D; head if ALL earlier
// neighbors in S; rE==0 -> prefix final -> serial diagonal chain resolves
// the tile exactly. Every published bit is exact.
// ---------------------------------------------------------------------------
struct SmC { u64 Dl[NT]; u64 Sl[NT]; u64 bw[3][4]; };

__device__ inline void round_body(const u64* __restrict__ mtile,
                                  u64* __restrict__ D, u64* __restrict__ S,
                                  SmC& sm, int gy) {
  int t = threadIdx.x;
  int w = t >> 6, l = t & 63;
  if (t < NT) sm.Dl[t] = D[t];
  else sm.Sl[t - NT] = S[t - NT];
  __syncthreads();
  u64 classified = sm.Dl[gy] | sm.Sl[gy];
  if (classified == ~0ull) return;   // uniform: tile done
  bool unk = !((classified >> l) & 1ull);
  u64 anyD = 0, anyU = 0, anyE = 0;
  if (unk) {
    int k0 = 32 * w, k1 = min(k0 + 32, gy + 1);
    for (int k = k0; k < k1; ++k) {
      u64 m = mtile[((size_t)gy * NT + k) * 64 + l];
      if (k == gy) {
        m &= (1ull << l) - 1ull;       // strictly earlier within own tile
        anyD |= m & sm.Dl[k];
        anyU |= m & ~sm.Sl[k];
      } else {
        anyD |= m & sm.Dl[k];
        anyU |= m & ~sm.Sl[k];
        anyE |= m & ~(sm.Sl[k] | sm.Dl[k]);  // external unknown
      }
    }
  }
  u64 bD = __ballot(anyD != 0ull), bU = __ballot(anyU != 0ull), bE = __ballot(anyE != 0ull);
  if (l == 0) { sm.bw[0][w] = bD; sm.bw[1][w] = bU; sm.bw[2][w] = bE; }
  __syncthreads();
  u64 rD = sm.bw[0][0] | sm.bw[0][1] | sm.bw[0][2] | sm.bw[0][3];
  u64 rU = sm.bw[1][0] | sm.bw[1][1] | sm.bw[1][2] | sm.bw[1][3];
  u64 rE = sm.bw[2][0] | sm.bw[2][1] | sm.bw[2][2] | sm.bw[2][3];
  u64 unkb = ~classified;
  if (rE == 0ull) {
    if (w == 0) {
      u64 dAA = mtile[((size_t)gy * NT + gy) * 64 + l];
      u64 heads = 0, todo = unkb & ~rD;
      while (todo) {
        int i = __builtin_ctzll(todo);
        heads |= 1ull << i;
        todo &= ~readlane64(dAA, i);   // clears i (diag) + in-tile suppressed
      }
      if (l == 0) {
        if (heads) atomicOr(&D[gy], heads);
        u64 ns = unkb & ~heads;
        if (ns) atomicOr(&S[gy], ns);
      }
    }
    return;
  }
  if (t == 0) {
    u64 newS = unkb & rD;
    u64 newD = unkb & ~rD & ~rU;
    if (newS) atomicOr(&S[gy], newS);
    if (newD) atomicOr(&D[gy], newD);
  }
}

__global__ __launch_bounds__(256) void k_round(const u64* __restrict__ mtile,
                                               u64* __restrict__ D,
                                               u64* __restrict__ S) {
  __shared__ SmC sm;
  round_body(mtile, D, S, sm, blockIdx.x);
}

// ---------------------------------------------------------------------------
// K4: merged final round + exact serial cleanup. Grid NT+1: blocks 0..NT-1
// run a normal round; block NT runs k_fix (wave 0 only, no barriers).
// Concurrency-safe: fix's snapshot is a sound monotone state; its final
// plain-store of D is the COMPLETE true head set, a superset of anything a
// concurrent round atomicOr's, so either write order leaves D complete.
// S is never read downstream. Fix reads row chunks l,64+l; chunks > jt are
// masked to 0 (upper triangle never written -> don't-care loads).
// ---------------------------------------------------------------------------
struct SmF { int ulist[N]; };
union SmRF { SmC c; SmF f; };

__global__ __launch_bounds__(256) void k_roundfix(const u64* __restrict__ mtile,
                                                  u64* __restrict__ D,
                                                  u64* __restrict__ S) {
  __shared__ SmRF sm;
  int b = blockIdx.x;
  if (b < NT) { round_body(mtile, D, S, sm.c, b); return; }
  if (threadIdx.x >= 64) return;   // fix: wave 0 only, barrier-free path
  int l = threadIdx.x;
  u64 D0 = D[l], D1 = D[64 + l];
  u64 S0 = S[l], S1 = S[64 + l];
  u64 u0 = ~(D0 | S0), u1 = ~(D1 | S1);
  int c0 = __popcll(u0), c1 = __popcll(u1);
  int p0 = c0, p1 = c1;
  for (int d = 1; d < 64; d <<= 1) {
    int v0 = __shfl_up(p0, d), v1 = __shfl_up(p1, d);
    if (l >= d) { p0 += v0; p1 += v1; }
  }
  int t0 = __shfl(p0, 63);
  int M = t0 + __shfl(p1, 63);
  {
    int o = p0 - c0; u64 v = u0;
    while (v) { int bb = __builtin_ctzll(v); v &= v - 1; sm.f.ulist[o++] = l * 64 + bb; }
    o = t0 + p1 - c1; v = u1;
    while (v) { int bb = __builtin_ctzll(v); v &= v - 1; sm.f.ulist[o++] = (64 + l) * 64 + bb; }
  }
  asm volatile("s_waitcnt lgkmcnt(0)" ::: "memory");  // in-wave LDS visibility
  if (M > 0) {
    u64 rx[8], ry[8];
    int pj[8];
    auto fetch = [&](int q, int j) {
      pj[q] = j;
      int jt = j >> 6, jl = j & 63;
      rx[q] = mtile[((size_t)jt * NT + l) * 64 + jl];       // masked if l > jt
      ry[q] = mtile[((size_t)jt * NT + 64 + l) * 64 + jl];  // masked if 64+l > jt
    };
#pragma unroll
    for (int q = 0; q < 8; ++q) fetch(q, sm.f.ulist[q < M ? q : M - 1]);
    for (int m = 0; m < M; ++m) {
      int slot = m & 7;
      int j = pj[slot];
      u64 vx = rx[slot], vy = ry[slot];
      int jt = j >> 6;                       // uniform
      u64 bm = (1ull << (j & 63)) - 1ull;
      u64 m0 = (l < jt) ? ~0ull : ((l == jt) ? bm : 0ull);
      u64 m1 = (64 + l < jt) ? ~0ull : ((64 + l == jt) ? bm : 0ull);
      bool hit = ((vx & D0 & m0) | (vy & D1 & m1)) != 0ull;
      bool head = (__ballot(hit) == 0ull);   // uniform
      u64 bset = 1ull << (j & 63);
      D0 |= (head && (l == jt)) ? bset : 0ull;
      D1 |= (head && (64 + l == jt)) ? bset : 0ull;
      int nm = m + 8;
      fetch(slot, sm.f.ulist[nm < M ? nm : M - 1]);
    }
  }
  D[l] = D0;
  D[64 + l] = D1;
}

// ---------------------------------------------------------------------------
// K5: cluster assignment + segment atomics. cluster[j] = min{h in D, h<=j,
// adj[h][j]} -> only lower-triangle chunks k<=gy needed; diag chunk masked
// to bits <= l ((2<<l)-1; l=63 wraps to ~0). Packed y2f=(by2<<32)|~j
// atomicMax = max-by2 min-j tiebreak (R11, validated).
// ---------------------------------------------------------------------------
__global__ __launch_bounds__(256) void k_cluster(const u64* __restrict__ mtile,
                                                 const u64* __restrict__ D,
                                                 const float* __restrict__ ss,
                                                 const float* __restrict__ by2s,
                                                 int* __restrict__ cluster,
                                                 int* __restrict__ cnt,
                                                 float* __restrict__ prob,
                                                 u64* __restrict__ y2f) {
  __shared__ u64 hlds[NT];
  __shared__ int red[4][64];
  int gy = blockIdx.x;
  if (threadIdx.x < NT) hlds[threadIdx.x] = D[threadIdx.x];
  __syncthreads();
  int w = threadIdx.x >> 6, l = threadIdx.x & 63;
  int best = 0x7fffffff;
  for (int kk = 0; kk < 32; ++kk) {
    int k = 32 * w + kk;
    if (k > gy) break;
    u64 m = mtile[((size_t)gy * NT + k) * 64 + l];
    if (k == gy) m &= (2ull << l) - 1ull;   // h <= j within diag chunk
    u64 v = m & hlds[k];
    if (v && best == 0x7fffffff) best = k * 64 + __builtin_ctzll(v);
  }
  red[w][l] = best;
  __syncthreads();
  if (w == 0) {
    int b = min(min(red[0][l], red[1][l]), min(red[2][l], red[3][l]));
    int j = gy * 64 + l;
    cluster[j] = b;
    atomicAdd(&cnt[b], 1);
    atomicAdd(&prob[b], ss[j]);
    u64 key = ((u64)__float_as_uint(by2s[j]) << 32) | (u32)(0xFFFFFFFFu - (u32)j);
    atomicMax(&y2f[b], key);           // by2 > 0 -> bits order == float order
  }
}

// ---------------------------------------------------------------------------
// K6: outputs. out[j][0..4] then keep[j] appended (floats 0/1).
// ---------------------------------------------------------------------------
__global__ __launch_bounds__(256) void k_out(const int* __restrict__ cluster,
                                             const float* __restrict__ bx1s, const float* __restrict__ by1s,
                                             const float* __restrict__ bx2s, const float* __restrict__ by2s,
                                             const int* __restrict__ cnt,
                                             const float* __restrict__ prob,
                                             const u64* __restrict__ y2f,
                                             const int* __restrict__ num_models,
                                             float* __restrict__ out) {
  int j = blockIdx.x * 256 + threadIdx.x;
  if (j >= N) return;
  int c = cluster[j];
  int nm = num_models[0];
  bool valid = (float)cnt[c] >= (float)nm / 3.0f;
  int jf = (int)(0xFFFFFFFFu - (u32)(y2f[c] & 0xFFFFFFFFull));
  bool keep = (jf == j) && valid;
  float o0 = 0.f, o1 = 0.f, o2 = 0.f, o3 = 0.f, o4 = 0.f;
  if (keep) {
    o0 = bx1s[j]; o1 = by1s[j]; o2 = bx2s[j]; o3 = by2s[j];
    o4 = prob[c] / (float)nm;
  }
  out[j * 5 + 0] = o0;
  out[j * 5 + 1] = o1;
  out[j * 5 + 2] = o2;
  out[j * 5 + 3] = o3;
  out[j * 5 + 4] = o4;
  out[N * 5 + j] = keep ? 1.0f : 0.0f;
}

// ---------------------------------------------------------------------------
extern "C" void kernel_launch(void* const* d_in, const int* in_sizes, int n_in,
                              void* d_out, int out_size, void* d_ws, size_t ws_size,
                              hipStream_t stream) {
  const float* boxes = (const float*)d_in[0];
  const float* scores = (const float*)d_in[1];
  const int* num_models = (const int*)d_in[2];
  float* out = (float*)d_out;

  char* p = (char*)d_ws;
  auto take = [&](size_t bytes) {
    char* r = p;
    p += (bytes + 255) & ~(size_t)255;
    return r;
  };
  float* bx1s = (float*)take((size_t)N * 4);
  float* by1s = (float*)take((size_t)N * 4);
  float* bx2s = (float*)take((size_t)N * 4);
  float* by2s = (float*)take((size_t)N * 4);
  float* ss   = (float*)take((size_t)N * 4);
  float* areas= (float*)take((size_t)N * 4);
  int* cluster= (int*)take((size_t)N * 4);
  int* cnt    = (int*)take((size_t)N * 4);
  float* prob = (float*)take((size_t)N * 4);
  u64* y2f    = (u64*)take((size_t)N * 8);            // packed (by2,~j)
  u64* D      = (u64*)take((size_t)NT * 8);           // head bitmap
  u64* S      = (u64*)take((size_t)NT * 8);           // suppressed bitmap
  u64* mtile  = (u64*)take((size_t)NT * NT * 64 * 8); // tiled adjacency (lower)

  k_rank0<<<N / 32, 256, 0, stream>>>(scores, boxes, bx1s, by1s, bx2s, by2s, ss, areas,
                                      cnt, prob, y2f, D, S);
  k_adj<<<(NT * (NT + 1) / 2 + 3) / 4, 256, 0, stream>>>(bx1s, by1s, bx2s, by2s, areas, mtile);
  for (int r = 0; r < NPLAIN; ++r)
    k_round<<<NT, 256, 0, stream>>>(mtile, D, S);
  k_roundfix<<<NT + 1, 256, 0, stream>>>(mtile, D, S);
  k_cluster<<<N / 64, 256, 0, stream>>>(mtile, D, ss, by2s, cluster, cnt, prob, y2f);
  k_out<<<N / 256, 256, 0, stream>>>(cluster, bx1s, by1s, bx2s, by2s, cnt, prob, y2f, num_models, out);
}